// Round 8
// baseline (800.002 us; speedup 1.0000x reference)
//
#include <hip/hip_runtime.h>
#include <hip/hip_bf16.h>

// Problem constants
#define Bsz   16
#define Tn    2048
#define INC   80
#define Hc    512
#define Dc    512
#define NCODE 1024
#define BT    (Bsz * Tn)           // 32768
#define RECON_N (Bsz * Tn * INC)   // 2,621,440
#define MARGIN 0.03f               // approx-distance safety margin

typedef __attribute__((ext_vector_type(8))) short bf16x8;
typedef __attribute__((ext_vector_type(4))) float f32x4;
typedef __attribute__((ext_vector_type(4))) unsigned short u16x4;

// float -> bf16 (round-to-nearest-even), and back
static __device__ __forceinline__ unsigned short f2bf(float x) {
    unsigned u = __float_as_uint(x);
    u += 0x7FFF + ((u >> 16) & 1);
    return (unsigned short)(u >> 16);
}
static __device__ __forceinline__ float bf2f(unsigned short h) {
    return __uint_as_float((unsigned)h << 16);
}

// async global->LDS 16B copy (global_load_lds_dwordx4).
typedef const __attribute__((address_space(1))) unsigned int* gas_p;
typedef __attribute__((address_space(3))) unsigned int* las_p;
static __device__ __forceinline__ void async16(const void* g, const void* l) {
    __builtin_amdgcn_global_load_lds(
        (gas_p)(unsigned long long)g,
        (las_p)(unsigned int)(unsigned long long)l,
        16, 0, 0);
}

// per-wave drain of this wave's outstanding VMEM (incl. global_load_lds).
// "memory" clobber orders subsequent ds_reads after the wait.
static __device__ __forceinline__ void wave_vm_drain() {
    asm volatile("s_waitcnt vmcnt(0)" ::: "memory");
}

// ---------------------------------------------------------------------------
// code_norms: CN[j] = sum_d CB[j][d]^2
// ---------------------------------------------------------------------------
__global__ __launch_bounds__(64)
void code_norms(const float* __restrict__ CB, float* __restrict__ CN) {
    int j = blockIdx.x;
    int lane = threadIdx.x;
    const float4* row = (const float4*)(CB + (size_t)j * Dc);
    float s = 0.f;
    #pragma unroll
    for (int i = 0; i < 2; ++i) {
        float4 v = row[lane + i * 64];
        s = fmaf(v.x, v.x, s);
        s = fmaf(v.y, v.y, s);
        s = fmaf(v.z, v.z, s);
        s = fmaf(v.w, v.w, s);
    }
    #pragma unroll
    for (int off = 32; off > 0; off >>= 1) s += __shfl_down(s, off, 64);
    if (lane == 0) CN[j] = s;
}

// ---------------------------------------------------------------------------
// cb_transpose: CBt[d][j] = CB[j][d].  grid (NCODE/64, Dc/64), block 256
// ---------------------------------------------------------------------------
__global__ __launch_bounds__(256)
void cb_transpose(const float* __restrict__ CB, float* __restrict__ CBt) {
    const int j0 = blockIdx.x * 64;
    const int d0 = blockIdx.y * 64;
    __shared__ float ts[64][65];
    const int tid = threadIdx.x;
    for (int i = tid; i < 4096; i += 256) {
        int r = i >> 6, c = i & 63;
        ts[r][c] = CB[(size_t)(j0 + r) * Dc + d0 + c];
    }
    __syncthreads();
    for (int i = tid; i < 4096; i += 256) {
        int r = i >> 6, c = i & 63;
        CBt[(size_t)(d0 + r) * NCODE + j0 + c] = ts[c][r];
    }
}

// ---------------------------------------------------------------------------
// mels_transpose: MT[b][c][t] = M[b][t][c].  grid (Tn/64, Bsz), block 256
// ---------------------------------------------------------------------------
__global__ __launch_bounds__(256)
void mels_transpose(const float* __restrict__ M, float* __restrict__ MT) {
    const int t0 = blockIdx.x * 64;
    const int b  = blockIdx.y;
    __shared__ float ts[64][84];
    const int tid = threadIdx.x;
    #pragma unroll
    for (int it = 0; it < 5; ++it) {
        int i = tid + it * 256;            // < 1280
        int t = i / 20, c4 = i % 20;
        *(float4*)&ts[t][c4 * 4] =
            *(const float4*)&M[((size_t)b * Tn + t0 + t) * INC + c4 * 4];
    }
    __syncthreads();
    #pragma unroll
    for (int it = 0; it < 20; ++it) {
        int i = tid + it * 256;            // < 5120
        int c = i >> 6, t = i & 63;
        MT[((size_t)b * INC + c) * Tn + t0 + t] = ts[t][c];
    }
}

// ---------------------------------------------------------------------------
// wt_transpose: Wt[(c*3+k)*Cout + o] = W[(o*Cin + c)*3 + k]
// ---------------------------------------------------------------------------
__global__ __launch_bounds__(256)
void wt_transpose(const float* __restrict__ W, float* __restrict__ Wt,
                  int Cin, int Cout) {
    const int o0 = blockIdx.x * 64;
    const int c0 = blockIdx.y * 16;
    __shared__ float ts[48][65];
    const int tid = threadIdx.x;
    for (int i = tid; i < 64 * 48; i += 256) {
        int o = i / 48, ck = i % 48;
        int oo = o0 + o;
        float v = 0.f;
        if (oo < Cout) v = W[(size_t)oo * Cin * 3 + c0 * 3 + ck];
        ts[ck][o] = v;
    }
    __syncthreads();
    for (int i = tid; i < 48 * 64; i += 256) {
        int o = i & 63, ck = i >> 6;
        int oo = o0 + o;
        if (oo < Cout) Wt[(size_t)(c0 * 3 + ck) * Cout + oo] = ts[ck][o];
    }
}

// ---------------------------------------------------------------------------
// wsplit: enc_w2 [o][c][k] fp32 -> Whl interleaved bf16
// [k][o][16 groups][hi32|lo32] so a lane's Ah/Al pair shares one cache line.
// ---------------------------------------------------------------------------
__global__ __launch_bounds__(256)
void wsplit(const float* __restrict__ W, unsigned short* __restrict__ Whl) {
    int o = blockIdx.x, k = blockIdx.y;
    #pragma unroll
    for (int it = 0; it < 2; ++it) {
        int c = threadIdx.x + it * 256;
        float v = W[((size_t)o * Hc + c) * 3 + k];
        unsigned short h = f2bf(v);
        size_t base = ((size_t)(k * Hc + o) * 16 + (c >> 5)) * 64 + (c & 31);
        Whl[base] = h;
        Whl[base + 32] = f2bf(v - bf2f(h));
    }
}

// ---------------------------------------------------------------------------
// wsplit80: dec_w2 [o][c][k] fp32 -> Wh2 [k][o][c] bf16 (hi only).
// ---------------------------------------------------------------------------
__global__ __launch_bounds__(256)
void wsplit80(const float* __restrict__ W, unsigned short* __restrict__ Wh) {
    int o = blockIdx.x, k = blockIdx.y;
    #pragma unroll
    for (int it = 0; it < 2; ++it) {
        int c = threadIdx.x + it * 256;
        Wh[((size_t)k * INC + o) * Hc + c] = f2bf(W[((size_t)o * Hc + c) * 3 + k]);
    }
}

// ---------------------------------------------------------------------------
// cbsplit: codebook [j][d] fp32 -> CBhl interleaved [j][16][hi32|lo32].
// ---------------------------------------------------------------------------
__global__ __launch_bounds__(256)
void cbsplit(const float* __restrict__ CB, unsigned short* __restrict__ CBhl) {
    int j = blockIdx.x;
    #pragma unroll
    for (int it = 0; it < 2; ++it) {
        int d = threadIdx.x + it * 256;
        float v = CB[(size_t)j * Dc + d];
        unsigned short h = f2bf(v);
        size_t base = ((size_t)j * 16 + (d >> 5)) * 64 + (d & 31);
        CBhl[base] = h;
        CBhl[base + 32] = f2bf(v - bf2f(h));
    }
}

// ---------------------------------------------------------------------------
// conv_enc1: melsT [B,80,T] -> y1hl interleaved bf16 hi/lo, K=3, ReLU.
// Guard-row zeroing folded in (blocks at t-extremes zero their o-slice).
// ---------------------------------------------------------------------------
__global__ __launch_bounds__(256)
void conv_enc1(const float* __restrict__ X, const float* __restrict__ Wt,
               const float* __restrict__ bias, unsigned short* __restrict__ Yhl) {
    const int t0 = blockIdx.x * 64;
    const int o0 = blockIdx.y * 128;
    const int b  = blockIdx.z;
    union SharedU {
        struct { float Xs[16][72]; float Ws[48][132]; } a;
        float Ys[128][69];
    };
    __shared__ __align__(16) SharedU su;
    float (&Xs)[16][72]  = su.a.Xs;
    float (&Ws)[48][132] = su.a.Ws;
    const int tid = threadIdx.x;
    const int tx = tid & 15, ty = tid >> 4;
    float acc[8][4] = {};
    const float* Xb = X + (size_t)b * INC * Tn;

    // guard rows (t=-1 and t=Tn): zero this block's 4 o-groups (256 ushorts)
    if (blockIdx.x == 0 && tid < 64) {
        u16x4 z4 = {0, 0, 0, 0};
        *(u16x4*)(Yhl + ((size_t)(b * (Tn + 2)) * 16 + (o0 >> 5)) * 64 + tid * 4) = z4;
    }
    if (blockIdx.x == Tn / 64 - 1 && tid < 64) {
        u16x4 z4 = {0, 0, 0, 0};
        *(u16x4*)(Yhl + ((size_t)(b * (Tn + 2) + Tn + 1) * 16 + (o0 >> 5)) * 64
                  + tid * 4) = z4;
    }

    for (int c0 = 0; c0 < INC; c0 += 16) {
        for (int i = tid; i < 16 * 66; i += 256) {
            int cc = i / 66, tt = i % 66;
            int t = t0 + tt - 1;
            float v = 0.f;
            if (t >= 0 && t < Tn) v = Xb[(size_t)(c0 + cc) * Tn + t];
            Xs[cc][tt] = v;
        }
        for (int i = tid; i < 48 * 128; i += 256) {
            int o = i & 127, ck = i >> 7;
            Ws[ck][o] = Wt[(size_t)(c0 * 3 + ck) * Hc + o0 + o];
        }
        __syncthreads();
        #pragma unroll
        for (int cc = 0; cc < 16; ++cc) {
            float4 xa = *(const float4*)&Xs[cc][tx * 4];
            float2 xb2 = *(const float2*)&Xs[cc][tx * 4 + 4];
            float xv[6] = {xa.x, xa.y, xa.z, xa.w, xb2.x, xb2.y};
            #pragma unroll
            for (int k = 0; k < 3; ++k) {
                float4 wa = *(const float4*)&Ws[cc * 3 + k][ty * 4];
                float4 wb = *(const float4*)&Ws[cc * 3 + k][64 + ty * 4];
                float wv[8] = {wa.x, wa.y, wa.z, wa.w, wb.x, wb.y, wb.z, wb.w};
                #pragma unroll
                for (int i8 = 0; i8 < 8; ++i8)
                    #pragma unroll
                    for (int j = 0; j < 4; ++j)
                        acc[i8][j] = fmaf(wv[i8], xv[k + j], acc[i8][j]);
            }
        }
        __syncthreads();
    }
    #pragma unroll
    for (int og = 0; og < 2; ++og)
        #pragma unroll
        for (int oi = 0; oi < 4; ++oi) {
            int ol = og * 64 + ty * 4 + oi;
            float bv = bias[o0 + ol];
            const int i8 = og * 4 + oi;
            #pragma unroll
            for (int j = 0; j < 4; ++j)
                su.Ys[ol][tx * 4 + j] = fmaxf(acc[i8][j] + bv, 0.f);
        }
    __syncthreads();
    #pragma unroll
    for (int it = 0; it < 8; ++it) {
        int i = tid + it * 256;            // 2048 = 32 o-quads x 64 t
        int oq = i & 31, t = i >> 5;
        int o4 = o0 + oq * 4;
        u16x4 h, l;
        #pragma unroll
        for (int r = 0; r < 4; ++r) {
            float v = su.Ys[oq * 4 + r][t];
            unsigned short hh = f2bf(v);
            h[r] = hh;
            l[r] = f2bf(v - bf2f(hh));
        }
        size_t base = ((size_t)(b * (Tn + 2) + 1 + t0 + t) * 16 + (o4 >> 5)) * 64
                      + (o4 & 31);
        *(u16x4*)(Yhl + base) = h;
        *(u16x4*)(Yhl + base + 32) = l;
    }
}

// ---------------------------------------------------------------------------
// conv_mid_mfma: implicit GEMM, WAVE-AUTONOMOUS double-buffering:
// each wave stages its private 72-row X window (its wn t-half) via
// global_load_lds into its own LDS region and syncs only on its own
// vmcnt(0) -- NO __syncthreads in the K-loop, so waves de-correlate and
// the matrix pipe stays fed. Triple-split epilogue staged via LDS with
// padded strides (conflict-free). Output bytes bit-identical to round 7.
// grid (Tn/128, Hc/128, B), block 256 (4 waves).
// ---------------------------------------------------------------------------
__global__ __launch_bounds__(256)
void conv_mid_mfma(const unsigned short* __restrict__ Xhl,
                   const unsigned short* __restrict__ Whl,
                   const float* __restrict__ bias,
                   unsigned short* __restrict__ Zt,
                   unsigned short* __restrict__ Lo2) {
    // XCD swizzle: lin%8 = XCD. XCD x -> b in {2x, 2x+1}; within: t-major, o inner.
    const int lin  = blockIdx.x + (blockIdx.y << 4) + (blockIdx.z << 6);
    const int slot = lin >> 3;                   // 0..127
    const int b  = ((lin & 7) << 1) | (slot >> 6);
    const int t0 = ((slot & 63) >> 2) << 7;      // t-block 0..15
    const int o0 = (slot & 3) << 7;              // o-block 0..3
    // 4 waves x 2 bufs x 72 rows x 64 ushorts = 73728 B
    __shared__ __align__(16) unsigned short pool[4 * 2 * 72 * 64];
    const int tid  = threadIdx.x;
    const int lane = tid & 63;
    const int wave = tid >> 6;
    const int wm = wave >> 1, wn = wave & 1;
    const int m16 = lane & 15;
    const int q = lane >> 4;
    const int lrow = lane >> 3;
    const int lchk = (lane & 7) ^ lrow;
    unsigned short* XW = pool + wave * (2 * 72 * 64);
    // per-wave global base: this wave's t-window starts at t0 + wn*64
    const unsigned short* XbW = Xhl + ((size_t)b * (Tn + 2) + t0 + wn * 64) * 1024
                                + (size_t)lrow * 1024 + lchk * 8;

    f32x4 acc[4][4];
    #pragma unroll
    for (int mt = 0; mt < 4; ++mt)
        #pragma unroll
        for (int nt = 0; nt < 4; ++nt)
            acc[mt][nt] = (f32x4){0.f, 0.f, 0.f, 0.f};

    // prologue: this wave stages c-group 0 into its buf 0 (9 x 8 rows)
    #pragma unroll
    for (int i = 0; i < 9; ++i)
        async16(XbW + (size_t)i * 8192, XW + i * 512);

    for (int c0 = 0; c0 < Hc; c0 += 32) {
        const int buf = (c0 >> 5) & 1;
        wave_vm_drain();                  // this wave's buf is ready
        if (c0 + 32 < Hc) {
            const unsigned short* src = XbW + (size_t)((c0 >> 5) + 1) * 64;
            #pragma unroll
            for (int i = 0; i < 9; ++i)
                async16(src + (size_t)i * 8192, XW + (buf ^ 1) * 4608 + i * 512);
        }
        #pragma unroll
        for (int k = 0; k < 3; ++k) {
            bf16x8 Ah[4], Al[4];
            #pragma unroll
            for (int mt = 0; mt < 4; ++mt) {
                int o = o0 + wm * 64 + mt * 16 + m16;
                size_t base = ((size_t)(k * Hc + o) * 16 + (c0 >> 5)) * 64 + q * 8;
                Ah[mt] = *(const bf16x8*)(Whl + base);
                Al[mt] = *(const bf16x8*)(Whl + base + 32);
            }
            #pragma unroll
            for (int nt = 0; nt < 4; ++nt) {
                int row = nt * 16 + m16 + k;             // local window row 0..65
                const unsigned short* rp = XW + buf * 4608 + row * 64;
                int ph = (q ^ (row & 7)) * 8;            // hi phys chunk
                union { bf16x8 v; uint4 u; } bh, bl;
                bh.u = *(const uint4*)(rp + ph);
                bl.u = *(const uint4*)(rp + (ph ^ 32));  // lo = hi slot ^ 4
                __builtin_amdgcn_s_setprio(1);
                #pragma unroll
                for (int mt = 0; mt < 4; ++mt)
                    acc[mt][nt] = __builtin_amdgcn_mfma_f32_16x16x32_bf16(
                        Ah[mt], bh.v, acc[mt][nt], 0, 0, 0);
                #pragma unroll
                for (int mt = 0; mt < 4; ++mt)
                    acc[mt][nt] = __builtin_amdgcn_mfma_f32_16x16x32_bf16(
                        Al[mt], bh.v, acc[mt][nt], 0, 0, 0);
                #pragma unroll
                for (int mt = 0; mt < 4; ++mt)
                    acc[mt][nt] = __builtin_amdgcn_mfma_f32_16x16x32_bf16(
                        Ah[mt], bl.v, acc[mt][nt], 0, 0, 0);
                __builtin_amdgcn_s_setprio(0);
            }
        }
    }
    // epilogue: stage through LDS (reuse pool), coalesced 512B/256B rows.
    // Padded strides (264/136 ushorts) -> writes land 4 banks apart (2-way max).
    __syncthreads();                     // all waves done with pool
    unsigned short* SZ = pool;           // [32][264]
    unsigned short* SL = pool + 32 * 264;// [32][136]
    unsigned short* Lb = Lo2 + (size_t)b * Tn * 512;
    const int g0 = o0 >> 5;
    #pragma unroll
    for (int p = 0; p < 4; ++p) {
        if (p) __syncthreads();          // staging buffer free
        if (wn == (p >> 1)) {
            #pragma unroll
            for (int nt2 = 0; nt2 < 2; ++nt2) {
                int nt = (p & 1) * 2 + nt2;
                int srow = nt2 * 16 + m16;   // 0..31
                #pragma unroll
                for (int mt = 0; mt < 4; ++mt) {
                    int lo = wm * 64 + mt * 16 + q * 4;   // local o 0..127
                    int ob = o0 + lo;
                    float4 bq = *(const float4*)&bias[ob];
                    float bqa[4] = {bq.x, bq.y, bq.z, bq.w};
                    u16x4 h, l, l2;
                    #pragma unroll
                    for (int r = 0; r < 4; ++r) {
                        float v = acc[mt][nt][r] + bqa[r];
                        unsigned short hh = f2bf(v);
                        float r1 = v - bf2f(hh);
                        unsigned short ll = f2bf(r1);
                        h[r] = hh;
                        l[r] = ll;
                        l2[r] = f2bf(r1 - bf2f(ll));
                    }
                    int gb = (lo >> 5) * 64 + (lo & 31);
                    *(u16x4*)&SZ[srow * 264 + gb] = h;
                    *(u16x4*)&SZ[srow * 264 + gb + 32] = l;
                    *(u16x4*)&SL[srow * 136 + lo] = l2;
                }
            }
        }
        __syncthreads();                 // staging data ready
        // Zt: 32 rows x 512B contiguous (64 lanes x 8B per row)
        #pragma unroll
        for (int it = 0; it < 8; ++it) {
            int i = tid + it * 256;
            int row = i >> 6, c = i & 63;
            *(u16x4*)(Zt + ((size_t)(b * Tn + t0 + p * 32 + row) * 16 + g0) * 64
                      + c * 4) = *(u16x4*)&SZ[row * 264 + c * 4];
        }
        // lo2: 32 rows x 256B contiguous (32 lanes x 8B per row)
        #pragma unroll
        for (int it = 0; it < 4; ++it) {
            int i = tid + it * 256;
            int row = i >> 5, c = i & 31;
            *(u16x4*)(Lb + (size_t)(t0 + p * 32 + row) * 512 + o0 + c * 4)
                = *(u16x4*)&SL[row * 136 + c * 4];
        }
    }
}

// ---------------------------------------------------------------------------
// dec2_mfma: recon = conv(y3t bf16, dec_w2) + b. async16 + XOR-swizzle,
// 64-c groups (single bf16), double-buffered. grid (Tn/128, 1, B), block 256.
// ---------------------------------------------------------------------------
__global__ __launch_bounds__(256)
void dec2_mfma(const unsigned short* __restrict__ Xt,
               const unsigned short* __restrict__ Wh2,
               const float* __restrict__ bias, float* __restrict__ OUT) {
    const int t0 = blockIdx.x * 128;
    const int b  = blockIdx.z;
    __shared__ __align__(16) unsigned short XL[2][136 * 64];  // 2 x 17408 B
    const int tid = threadIdx.x;
    const int lane = tid & 63;
    const int wave = tid >> 6;
    const int wn = wave;               // wave = t-quadrant (32 t each)
    const int m16 = lane & 15;
    const int q = lane >> 4;
    const int lrow = lane >> 3;
    const int lchk = (lane & 7) ^ lrow;
    const unsigned short* Xb = Xt + ((size_t)b * (Tn + 2) + t0) * 512
                               + (size_t)lrow * 512 + lchk * 8;

    f32x4 acc[5][2];
    #pragma unroll
    for (int mt = 0; mt < 5; ++mt)
        #pragma unroll
        for (int nt = 0; nt < 2; ++nt)
            acc[mt][nt] = (f32x4){0.f, 0.f, 0.f, 0.f};

    #pragma unroll
    for (int i = 0; i < 5; ++i) {
        int ii = wave + i * 4;
        if (ii < 17)
            async16(Xb + (size_t)ii * 4096, &XL[0][ii * 512]);
    }

    for (int c0 = 0; c0 < Hc; c0 += 64) {
        const int buf = (c0 >> 6) & 1;
        __syncthreads();
        if (c0 + 64 < Hc) {
            const unsigned short* src = Xb + (size_t)((c0 >> 6) + 1) * 64;
            #pragma unroll
            for (int i = 0; i < 5; ++i) {
                int ii = wave + i * 4;
                if (ii < 17)
                    async16(src + (size_t)ii * 4096, &XL[buf ^ 1][ii * 512]);
            }
        }
        #pragma unroll
        for (int k = 0; k < 3; ++k) {
            #pragma unroll
            for (int sub = 0; sub < 2; ++sub) {
                int c = c0 + sub * 32;
                bf16x8 Ah[5];
                #pragma unroll
                for (int mt = 0; mt < 5; ++mt) {
                    int o = mt * 16 + m16;
                    Ah[mt] = *(const bf16x8*)(Wh2 + ((size_t)(k * INC + o)) * Hc
                                              + c + q * 8);
                }
                #pragma unroll
                for (int nt = 0; nt < 2; ++nt) {
                    int row = wn * 32 + nt * 16 + m16 + k;   // 0..129
                    const unsigned short* rp = &XL[buf][row * 64];
                    int p = sub * 4 + q;
                    int ph = (p ^ (row & 7)) * 8;
                    union { bf16x8 v; uint4 u; } bh;
                    bh.u = *(const uint4*)(rp + ph);
                    #pragma unroll
                    for (int mt = 0; mt < 5; ++mt)
                        acc[mt][nt] = __builtin_amdgcn_mfma_f32_16x16x32_bf16(
                            Ah[mt], bh.v, acc[mt][nt], 0, 0, 0);
                }
            }
        }
    }
    #pragma unroll
    for (int mt = 0; mt < 5; ++mt) {
        float4 bq = *(const float4*)&bias[mt * 16 + q * 4];
        #pragma unroll
        for (int nt = 0; nt < 2; ++nt) {
            int t = t0 + wn * 32 + nt * 16 + m16;
            float4 r;
            r.x = acc[mt][nt][0] + bq.x;
            r.y = acc[mt][nt][1] + bq.y;
            r.z = acc[mt][nt][2] + bq.z;
            r.w = acc[mt][nt][3] + bq.w;
            *(float4*)(OUT + ((size_t)b * Tn + t) * INC + mt * 16 + q * 4) = r;
        }
    }
}

// ---------------------------------------------------------------------------
// vq_mfma: approx distances via 3xbf16 MFMA GEMM reading Zt.
// WAVE-AUTONOMOUS double-buffering (no K-loop barriers): each wave stages
// its 64-row Zt window privately, syncs on its own vmcnt(0).
// grid (BT/128, NCODE/128) = 2048 blocks, block 256.
// ---------------------------------------------------------------------------
__global__ __launch_bounds__(256)
void vq_mfma(const unsigned short* __restrict__ Zt,
             const unsigned short* __restrict__ CBhl,
             const float* __restrict__ CN,
             float* __restrict__ candv, int* __restrict__ candi,
             float* __restrict__ cand2v) {
    // XCD swizzle: lin%8 = XCD; XCD x -> nb in [32x, 32x+32) (2 batches), all jb.
    const int lin  = blockIdx.x + (blockIdx.y << 8);
    const int slotB = lin >> 3;                  // 0..255
    const int nb = ((lin & 7) << 5) | (slotB & 31);
    const int jb = slotB >> 5;                   // 0..7
    const int b  = nb >> 4;
    const int t0 = (nb & 15) * 128;
    const int jbase = jb * 128;
    // 4 waves x 2 bufs x 64 rows x 64 ushorts = 65536 B; reduction aliased.
    __shared__ __align__(16) unsigned short vpool[4 * 2 * 64 * 64];
    float* RV = (float*)vpool;
    int*   RI = (int*)((char*)vpool + 4096);
    float* R2 = (float*)((char*)vpool + 8192);

    const int tid = threadIdx.x;
    const int lane = tid & 63;
    const int wave = tid >> 6;
    const int wm = wave >> 1, wn = wave & 1;
    const int m16 = lane & 15;
    const int q = lane >> 4;
    const int lrow = lane >> 3;
    const int lchk = (lane & 7) ^ lrow;
    unsigned short* XW = vpool + wave * (2 * 64 * 64);
    const unsigned short* ZbW = Zt + (size_t)(b * Tn + t0 + wn * 64) * 1024
                                + (size_t)lrow * 1024 + lchk * 8;

    f32x4 acc[4][4];
    #pragma unroll
    for (int mt = 0; mt < 4; ++mt)
        #pragma unroll
        for (int nt = 0; nt < 4; ++nt)
            acc[mt][nt] = (f32x4){0.f, 0.f, 0.f, 0.f};

    // prologue: stage d-group 0 into this wave's buf 0 (8 x 8 rows)
    #pragma unroll
    for (int i = 0; i < 8; ++i)
        async16(ZbW + (size_t)i * 8192, XW + i * 512);

    for (int d0 = 0; d0 < Dc; d0 += 32) {
        const int buf = (d0 >> 5) & 1;
        wave_vm_drain();                  // this wave's buf is ready
        if (d0 + 32 < Dc) {
            const unsigned short* src = ZbW + (size_t)((d0 >> 5) + 1) * 64;
            #pragma unroll
            for (int i = 0; i < 8; ++i)
                async16(src + (size_t)i * 8192, XW + (buf ^ 1) * 4096 + i * 512);
        }
        bf16x8 Ah[4], Al[4];
        #pragma unroll
        for (int mt = 0; mt < 4; ++mt) {
            int j = jbase + wm * 64 + mt * 16 + m16;
            size_t base = ((size_t)j * 16 + (d0 >> 5)) * 64 + q * 8;
            Ah[mt] = *(const bf16x8*)(CBhl + base);
            Al[mt] = *(const bf16x8*)(CBhl + base + 32);
        }
        #pragma unroll
        for (int nt = 0; nt < 4; ++nt) {
            int row = nt * 16 + m16;                 // local window row 0..63
            const unsigned short* rp = XW + buf * 4096 + row * 64;
            int ph = (q ^ (row & 7)) * 8;
            union { bf16x8 v; uint4 u; } bh, bl;
            bh.u = *(const uint4*)(rp + ph);
            bl.u = *(const uint4*)(rp + (ph ^ 32));
            __builtin_amdgcn_s_setprio(1);
            #pragma unroll
            for (int mt = 0; mt < 4; ++mt)
                acc[mt][nt] = __builtin_amdgcn_mfma_f32_16x16x32_bf16(
                    Ah[mt], bh.v, acc[mt][nt], 0, 0, 0);
            #pragma unroll
            for (int mt = 0; mt < 4; ++mt)
                acc[mt][nt] = __builtin_amdgcn_mfma_f32_16x16x32_bf16(
                    Al[mt], bh.v, acc[mt][nt], 0, 0, 0);
            #pragma unroll
            for (int mt = 0; mt < 4; ++mt)
                acc[mt][nt] = __builtin_amdgcn_mfma_f32_16x16x32_bf16(
                    Ah[mt], bl.v, acc[mt][nt], 0, 0, 0);
            __builtin_amdgcn_s_setprio(0);
        }
    }
    __syncthreads();                      // pool reuse for reduction

    float cn4[4][4];
    #pragma unroll
    for (int mt = 0; mt < 4; ++mt) {
        float4 c = *(const float4*)&CN[jbase + wm * 64 + mt * 16 + q * 4];
        cn4[mt][0] = c.x; cn4[mt][1] = c.y; cn4[mt][2] = c.z; cn4[mt][3] = c.w;
    }
    #pragma unroll
    for (int nt = 0; nt < 4; ++nt) {
        int t = wn * 64 + nt * 16 + m16;
        float v1 = 1e30f, v2 = 1e30f;
        int i1 = 0;
        #pragma unroll
        for (int mt = 0; mt < 4; ++mt)
            #pragma unroll
            for (int r = 0; r < 4; ++r) {
                float d = fmaf(-2.f, acc[mt][nt][r], cn4[mt][r]);
                int j = jbase + wm * 64 + mt * 16 + q * 4 + r;
                if (d < v1 || (d == v1 && j < i1)) { v2 = v1; v1 = d; i1 = j; }
                else if (d < v2) v2 = d;
            }
        int slotw = wm * 4 + q;
        RV[t * 8 + slotw] = v1;
        RI[t * 8 + slotw] = i1;
        R2[t * 8 + slotw] = v2;
    }
    __syncthreads();
    if (tid < 128) {
        int t = tid;
        float v1 = RV[t * 8], v2 = R2[t * 8];
        int i1 = RI[t * 8];
        #pragma unroll
        for (int s = 1; s < 8; ++s) {
            float a1 = RV[t * 8 + s], a2 = R2[t * 8 + s];
            int ai = RI[t * 8 + s];
            if (a1 < v1 || (a1 == v1 && ai < i1)) {
                v2 = fminf(v1, a2); v1 = a1; i1 = ai;
            } else {
                v2 = fminf(v2, a1);
            }
        }
        int n = b * Tn + t0 + t;
        candv[(size_t)jb * BT + n] = v1;
        candi[(size_t)jb * BT + n] = i1;
        cand2v[(size_t)jb * BT + n] = v2;
    }
}

// ---------------------------------------------------------------------------
// vq_reduce2: merge 8 j-block candidates; flag near-ties for exact rescore.
// ---------------------------------------------------------------------------
__global__ __launch_bounds__(256)
void vq_reduce2(const float* __restrict__ candv, const int* __restrict__ candi,
                const float* __restrict__ cand2v, int* __restrict__ idxI,
                float* __restrict__ idxf, int* __restrict__ flagn,
                int* __restrict__ flaglist) {
    int n = blockIdx.x * 256 + threadIdx.x;
    float v1 = candv[n], v2 = cand2v[n];
    int i1 = candi[n];
    #pragma unroll
    for (int jq = 1; jq < 8; ++jq) {
        float a1 = candv[(size_t)jq * BT + n];
        float a2 = cand2v[(size_t)jq * BT + n];
        int ai = candi[(size_t)jq * BT + n];
        if (a1 < v1 || (a1 == v1 && ai < i1)) {
            v2 = fminf(v1, a2); v1 = a1; i1 = ai;
        } else {
            v2 = fminf(v2, a1);
        }
    }
    idxI[n] = i1;
    idxf[n] = (float)i1;
    if (v2 - v1 < MARGIN) {
        int s = atomicAdd(flagn, 1);
        flaglist[s] = n;
    }
}

// ---------------------------------------------------------------------------
// vq_rescue: near-exact re-score of flagged positions over all 1024 codes.
// z reconstructed as hi+lo+lo2 (error <= 2^-27 |z|).
// ---------------------------------------------------------------------------
__global__ __launch_bounds__(256)
void vq_rescue(const int* __restrict__ flagn, const int* __restrict__ flaglist,
               const unsigned short* __restrict__ Zt,
               const unsigned short* __restrict__ Lo2,
               const float* __restrict__ CB,
               const float* __restrict__ CN, int* __restrict__ idxI,
               float* __restrict__ idxf) {
    __shared__ float zs[512];
    __shared__ float rvv[256];
    __shared__ int   rii[256];
    const int nf = *flagn;
    for (int f = blockIdx.x; f < nf; f += gridDim.x) {
        int n = flaglist[f];
        __syncthreads();
        #pragma unroll
        for (int it = 0; it < 2; ++it) {
            int d = threadIdx.x + it * 256;
            const unsigned short* zr = Zt + ((size_t)n * 16 + (d >> 5)) * 64
                                       + (d & 31);
            zs[d] = bf2f(zr[0]) + bf2f(zr[32]) + bf2f(Lo2[(size_t)n * 512 + d]);
        }
        __syncthreads();
        float bv = 1e30f;
        int bi = 0;
        #pragma unroll
        for (int jj = 0; jj < 4; ++jj) {
            int j = threadIdx.x * 4 + jj;
            const float* cr = CB + (size_t)j * Dc;
            float dot = 0.f;
            for (int d = 0; d < Dc; ++d) dot = fmaf(zs[d], cr[d], dot);
            float dist = fmaf(-2.f, dot, CN[j]);
            if (dist < bv || (dist == bv && j < bi)) { bv = dist; bi = j; }
        }
        rvv[threadIdx.x] = bv;
        rii[threadIdx.x] = bi;
        __syncthreads();
        for (int off = 128; off > 0; off >>= 1) {
            if (threadIdx.x < off) {
                float ov = rvv[threadIdx.x + off];
                int oi = rii[threadIdx.x + off];
                if (ov < rvv[threadIdx.x] ||
                    (ov == rvv[threadIdx.x] && oi < rii[threadIdx.x])) {
                    rvv[threadIdx.x] = ov; rii[threadIdx.x] = oi;
                }
            }
            __syncthreads();
        }
        if (threadIdx.x == 0) {
            idxI[n] = rii[0];
            idxf[n] = (float)rii[0];
        }
    }
}

// ---------------------------------------------------------------------------
// gemm_g: G[j][kk*512+o] = sum_c CB[j][c] * dec_w1[o][c][kk].
// ---------------------------------------------------------------------------
__global__ __launch_bounds__(256)
void gemm_g(const float* __restrict__ CBt, const float* __restrict__ Wt,
            float* __restrict__ G) {
    const int j0 = blockIdx.x * 64;
    const int kk = blockIdx.y >> 2;
    const int o0 = (blockIdx.y & 3) * 128;
    __shared__ __align__(16) float As[16][68];
    __shared__ __align__(16) float Bs[16][132];
    const int tid = threadIdx.x;
    const int tx = tid & 15, ty = tid >> 4;
    float acc[4][8] = {};

    for (int c0 = 0; c0 < Dc; c0 += 16) {
        {
            int cc = tid >> 4, j4 = tid & 15;
            *(float4*)&As[cc][j4 * 4] =
                *(const float4*)&CBt[(size_t)(c0 + cc) * NCODE + j0 + j4 * 4];
        }
        #pragma unroll
        for (int it = 0; it < 2; ++it) {
            int i = tid + it * 256;
            int cc = i >> 5, o4 = i & 31;
            *(float4*)&Bs[cc][o4 * 4] =
                *(const float4*)&Wt[(size_t)((c0 + cc) * 3 + kk) * Hc + o0 + o4 * 4];
        }
        __syncthreads();
        #pragma unroll
        for (int cc = 0; cc < 16; ++cc) {
            float4 a = *(const float4*)&As[cc][tx * 4];
            float av[4] = {a.x, a.y, a.z, a.w};
            float4 b0 = *(const float4*)&Bs[cc][ty * 4];
            float4 b1 = *(const float4*)&Bs[cc][64 + ty * 4];
            float bv[8] = {b0.x, b0.y, b0.z, b0.w, b1.x, b1.y, b1.z, b1.w};
            #pragma unroll
            for (int jj = 0; jj < 4; ++jj)
                #pragma unroll
                for (int oo = 0; oo < 8; ++oo)
                    acc[jj][oo] = fmaf(av[jj], bv[oo], acc[jj][oo]);
        }
        __syncthreads();
    }
    #pragma unroll
    for (int jj = 0; jj < 4; ++jj) {
        int j = j0 + tx * 4 + jj;
        float* gp = G + (size_t)j * 1536 + kk * 512 + o0;
        *(float4*)(gp + ty * 4) = *(float4*)&acc[jj][0];
        *(float4*)(gp + 64 + ty * 4) = *(float4*)&acc[jj][4];
    }
}

// ---------------------------------------------------------------------------
// dec_y3: y3t[b][t][o] (bf16, rows of 512, guards folded in) =
//   f2bf(relu(b1[o] + sum_kk G[idx[b][t+kk-1]][kk*512+o])).
// ---------------------------------------------------------------------------
__global__ __launch_bounds__(256)
void dec_y3(const int* __restrict__ idx, const float* __restrict__ G,
            const float* __restrict__ bias, unsigned short* __restrict__ Yt) {
    const int t0 = blockIdx.x * 64;
    const int o0 = blockIdx.y * 128;
    const int b  = blockIdx.z;
    const int tid = threadIdx.x;
    __shared__ int sidx[66];
    __shared__ __align__(16) float Ys[128][68];

    // guard rows (t=-1 and t=Tn): zero this block's o-slice (128 ushorts)
    if (blockIdx.x == 0 && tid < 32) {
        u16x4 z4 = {0, 0, 0, 0};
        *(u16x4*)(Yt + (size_t)(b * (Tn + 2)) * 512 + o0 + tid * 4) = z4;
    }
    if (blockIdx.x == Tn / 64 - 1 && tid < 32) {
        u16x4 z4 = {0, 0, 0, 0};
        *(u16x4*)(Yt + (size_t)(b * (Tn + 2) + Tn + 1) * 512 + o0 + tid * 4) = z4;
    }

    if (tid < 66) {
        int t = t0 + tid - 1;
        sidx[tid] = (t >= 0 && t < Tn) ? idx[b * Tn + t] : -1;
    }
    __syncthreads();

    const int o = tid & 127;
    const int half = tid >> 7;
    float acc[32] = {};
    #pragma unroll
    for (int kk = 0; kk < 3; ++kk) {
        const float* Gk = G + (size_t)kk * 512 + o0 + o;
        #pragma unroll
        for (int k = 0; k < 32; ++k) {
            int j = sidx[half + 2 * k + kk];
            if (j >= 0) acc[k] += Gk[(size_t)j * 1536];
        }
    }
    float bv = bias[o0 + o];
    #pragma unroll
    for (int k = 0; k < 32; ++k)
        Ys[o][half + 2 * k] = fmaxf(acc[k] + bv, 0.f);
    __syncthreads();

    unsigned short* Yb = Yt + ((size_t)(b * (Tn + 2) + 1 + t0)) * 512 + o0;
    #pragma unroll
    for (int it = 0; it < 8; ++it) {
        int i = tid + it * 256;            // 2048 = 32 o-quads x 64 t
        int t = i >> 5, oq = i & 31;
        u16x4 h;
        #pragma unroll
        for (int r = 0; r < 4; ++r)
            h[r] = f2bf(Ys[oq * 4 + r][t]);
        *(u16x4*)(Yb + (size_t)t * 512 + oq * 4) = h;
    }
}

// ---------------------------------------------------------------------------
extern "C" void kernel_launch(void* const* d_in, const int* in_sizes, int n_in,
                              void* d_out, int out_size, void* d_ws, size_t ws_size,
                              hipStream_t stream) {
    const float* mels    = (const float*)d_in[0];
    const float* enc_w1  = (const float*)d_in[1];
    const float* enc_b1  = (const float*)d_in[2];
    const float* enc_w2  = (const float*)d_in[3];
    const float* enc_b2  = (const float*)d_in[4];
    const float* codebook= (const float*)d_in[5];
    const float* dec_w1  = (const float*)d_in[6];
    const float* dec_b1  = (const float*)d_in[7];
    const float* dec_w2  = (const float*)d_in[8];
    const float* dec_b2  = (const float*)d_in[9];

    float* out = (float*)d_out;
    float* recon = out;                 // [B,T,80]
    float* idxf  = out + RECON_N;       // [B,T] as float

    const size_t ACT = (size_t)Bsz * Hc * Tn;          // 16,777,216 floats
    const size_t Y1HL_U = (size_t)Bsz * (Tn + 2) * 1024 + 16384; // ushorts+slack
    const size_t R2F = Y1HL_U / 2;                      // floats

    // Region R1 (67 MB): Zt interleaved hi/lo (conv_mid out, vq+rescue read)
    //                    -> later y3t bf16 (dec path, after rescue)
    unsigned short* Zt  = (unsigned short*)d_ws;        // [BT*1024] ushorts
    unsigned short* y3t = (unsigned short*)d_ws;        // aliases Zt post-rescue
    // Region R2 (67 MB): y1hl interleaved (enc1 out, conv_mid in)
    float* r2 = (float*)d_ws + ACT;
    unsigned short* y1hl = (unsigned short*)r2;
    // small region
    float* sm    = r2 + R2F;
    int*   idxI  = (int*)sm;                            // [BT]
    float* cn    = (float*)(idxI + BT);                 // [NCODE]
    float* cbt   = cn + NCODE;                          // [Dc*NCODE]
    float* wt1   = cbt + (size_t)Dc * NCODE;            // enc_w1t: 80*3*512
    float* wt3   = wt1 + (size_t)INC * 3 * Hc;          // dec_w1t: 512*3*512
    float* candv = wt3 + (size_t)Dc * 3 * Hc;           // [8*BT]
    float* cand2v= candv + (size_t)8 * BT;              // [8*BT]
    int*   candi = (int*)(cand2v + (size_t)8 * BT);     // [8*BT]
    int*   flagn = candi + (size_t)8 * BT;              // [4]
    int*   flaglist = flagn + 4;                        // [BT]
    float* G     = (float*)(flaglist + BT);             // [NCODE*1536]
    unsigned short* whl  = (unsigned short*)(G + (size_t)NCODE * 1536); // [3*Hc*1024]
    unsigned short* cbhl = whl + (size_t)3 * Hc * 1024;                 // [NCODE*1024]
    unsigned short* wh2  = cbhl + (size_t)NCODE * 1024;                 // [3*INC*Hc]
    float* melsT = (float*)(wh2 + (size_t)3 * INC * Hc);                // [B,80,T]
    // lo2 residual plane [BT*512] ushorts; aliases melsT (dead after enc1)
    unsigned short* lo2 = (unsigned short*)melsT;

    dim3 blk(256);
    hipMemsetAsync(flagn, 0, 16, stream);
    // prep: norms + transposes + bf16 splits
    code_norms<<<dim3(NCODE), dim3(64), 0, stream>>>(codebook, cn);
    cb_transpose<<<dim3(NCODE / 64, Dc / 64), blk, 0, stream>>>(codebook, cbt);
    mels_transpose<<<dim3(Tn / 64, Bsz), blk, 0, stream>>>(mels, melsT);
    wt_transpose<<<dim3(Hc / 64, INC / 16), blk, 0, stream>>>(enc_w1, wt1, INC, Hc);
    wsplit<<<dim3(Hc, 3), blk, 0, stream>>>(enc_w2, whl);
    cbsplit<<<dim3(NCODE), blk, 0, stream>>>(codebook, cbhl);
    wt_transpose<<<dim3(Hc / 64, Dc / 16), blk, 0, stream>>>(dec_w1, wt3, Dc, Hc);
    wsplit80<<<dim3(INC, 3), blk, 0, stream>>>(dec_w2, wh2);
    // decoder conv1 folded matrix (independent of activations)
    gemm_g<<<dim3(NCODE / 64, 12), blk, 0, stream>>>(cbt, wt3, G);
    // encoder (enc1 writes interleaved y1hl + its guard rows)
    conv_enc1<<<dim3(Tn / 64, Hc / 128, Bsz), blk, 0, stream>>>(melsT, wt1, enc_b1,
                                                                y1hl);
    // conv_mid: wave-autonomous dbuf; writes Zt (hi/lo) + lo2 residual
    conv_mid_mfma<<<dim3(Tn / 128, Hc / 128, Bsz), blk, 0, stream>>>(y1hl, whl,
                                                                     enc_b2,
                                                                     Zt, lo2);
    // vector quantization: MFMA approx + margin-guarded near-exact rescue
    vq_mfma<<<dim3(BT / 128, NCODE / 128), blk, 0, stream>>>(Zt, cbhl, cn,
                                                             candv, candi, cand2v);
    vq_reduce2<<<dim3(BT / 256), blk, 0, stream>>>(candv, candi, cand2v, idxI,
                                                   idxf, flagn, flaglist);
    vq_rescue<<<dim3(128), blk, 0, stream>>>(flagn, flaglist, Zt, lo2, codebook,
                                             cn, idxI, idxf);
    // decoder: conv1 via gather of G rows (bf16 out + guards), conv2 via MFMA
    dec_y3<<<dim3(Tn / 64, 4, Bsz), blk, 0, stream>>>(idxI, G, dec_b1, y3t);
    dec2_mfma<<<dim3(Tn / 128, 1, Bsz), blk, 0, stream>>>(y3t, wh2, dec_b2, recon);
}

// Round 10
// 665.854 us; speedup vs baseline: 1.2015x; 1.2015x over previous
//
#include <hip/hip_runtime.h>
#include <hip/hip_bf16.h>

// Problem constants
#define Bsz   16
#define Tn    2048
#define INC   80
#define Hc    512
#define Dc    512
#define NCODE 1024
#define BT    (Bsz * Tn)           // 32768
#define RECON_N (Bsz * Tn * INC)   // 2,621,440
#define MARGIN 0.03f               // approx-distance safety margin

typedef __attribute__((ext_vector_type(8))) short bf16x8;
typedef __attribute__((ext_vector_type(4))) float f32x4;
typedef __attribute__((ext_vector_type(4))) unsigned short u16x4;

// float -> bf16 (round-to-nearest-even), and back
static __device__ __forceinline__ unsigned short f2bf(float x) {
    unsigned u = __float_as_uint(x);
    u += 0x7FFF + ((u >> 16) & 1);
    return (unsigned short)(u >> 16);
}
static __device__ __forceinline__ float bf2f(unsigned short h) {
    return __uint_as_float((unsigned)h << 16);
}

// async global->LDS 16B copy (global_load_lds_dwordx4).
typedef const __attribute__((address_space(1))) unsigned int* gas_p;
typedef __attribute__((address_space(3))) unsigned int* las_p;
static __device__ __forceinline__ void async16(const void* g, const void* l) {
    __builtin_amdgcn_global_load_lds(
        (gas_p)(unsigned long long)g,
        (las_p)(unsigned int)(unsigned long long)l,
        16, 0, 0);
}

// per-wave drain of this wave's outstanding VMEM (incl. global_load_lds).
static __device__ __forceinline__ void wave_vm_drain() {
    asm volatile("s_waitcnt vmcnt(0)" ::: "memory");
}

// MFMA A-fragment register set: 4 hi + 4 lo bf16x8 (one per mt tile).
struct AFrag { bf16x8 h[4]; bf16x8 l[4]; };

// load a 4-tile A-fragment group from fragment-packed storage:
// block (idx) = 1024 contiguous ushorts: [hi 512 | lo 512], lane-major.
static __device__ __forceinline__ void load_afrag(
        const unsigned short* __restrict__ Wf, int blk0, int lane, AFrag& A) {
    #pragma unroll
    for (int mt = 0; mt < 4; ++mt) {
        const unsigned short* p = Wf + ((size_t)(blk0 + mt) << 10) + lane * 8;
        A.h[mt] = *(const bf16x8*)p;
        A.l[mt] = *(const bf16x8*)(p + 512);
    }
}

// ---------------------------------------------------------------------------
// code_norms: CN[j] = sum_d CB[j][d]^2
// ---------------------------------------------------------------------------
__global__ __launch_bounds__(64)
void code_norms(const float* __restrict__ CB, float* __restrict__ CN) {
    int j = blockIdx.x;
    int lane = threadIdx.x;
    const float4* row = (const float4*)(CB + (size_t)j * Dc);
    float s = 0.f;
    #pragma unroll
    for (int i = 0; i < 2; ++i) {
        float4 v = row[lane + i * 64];
        s = fmaf(v.x, v.x, s);
        s = fmaf(v.y, v.y, s);
        s = fmaf(v.z, v.z, s);
        s = fmaf(v.w, v.w, s);
    }
    #pragma unroll
    for (int off = 32; off > 0; off >>= 1) s += __shfl_down(s, off, 64);
    if (lane == 0) CN[j] = s;
}

// ---------------------------------------------------------------------------
// cb_transpose: CBt[d][j] = CB[j][d].  grid (NCODE/64, Dc/64), block 256
// ---------------------------------------------------------------------------
__global__ __launch_bounds__(256)
void cb_transpose(const float* __restrict__ CB, float* __restrict__ CBt) {
    const int j0 = blockIdx.x * 64;
    const int d0 = blockIdx.y * 64;
    __shared__ float ts[64][65];
    const int tid = threadIdx.x;
    for (int i = tid; i < 4096; i += 256) {
        int r = i >> 6, c = i & 63;
        ts[r][c] = CB[(size_t)(j0 + r) * Dc + d0 + c];
    }
    __syncthreads();
    for (int i = tid; i < 4096; i += 256) {
        int r = i >> 6, c = i & 63;
        CBt[(size_t)(d0 + r) * NCODE + j0 + c] = ts[c][r];
    }
}

// ---------------------------------------------------------------------------
// mels_transpose: MT[b][c][t] = M[b][t][c].  grid (Tn/64, Bsz), block 256
// ---------------------------------------------------------------------------
__global__ __launch_bounds__(256)
void mels_transpose(const float* __restrict__ M, float* __restrict__ MT) {
    const int t0 = blockIdx.x * 64;
    const int b  = blockIdx.y;
    __shared__ float ts[64][84];
    const int tid = threadIdx.x;
    #pragma unroll
    for (int it = 0; it < 5; ++it) {
        int i = tid + it * 256;            // < 1280
        int t = i / 20, c4 = i % 20;
        *(float4*)&ts[t][c4 * 4] =
            *(const float4*)&M[((size_t)b * Tn + t0 + t) * INC + c4 * 4];
    }
    __syncthreads();
    #pragma unroll
    for (int it = 0; it < 20; ++it) {
        int i = tid + it * 256;            // < 5120
        int c = i >> 6, t = i & 63;
        MT[((size_t)b * INC + c) * Tn + t0 + t] = ts[t][c];
    }
}

// ---------------------------------------------------------------------------
// wt_transpose: Wt[(c*3+k)*Cout + o] = W[(o*Cin + c)*3 + k]
// ---------------------------------------------------------------------------
__global__ __launch_bounds__(256)
void wt_transpose(const float* __restrict__ W, float* __restrict__ Wt,
                  int Cin, int Cout) {
    const int o0 = blockIdx.x * 64;
    const int c0 = blockIdx.y * 16;
    __shared__ float ts[48][65];
    const int tid = threadIdx.x;
    for (int i = tid; i < 64 * 48; i += 256) {
        int o = i / 48, ck = i % 48;
        int oo = o0 + o;
        float v = 0.f;
        if (oo < Cout) v = W[(size_t)oo * Cin * 3 + c0 * 3 + ck];
        ts[ck][o] = v;
    }
    __syncthreads();
    for (int i = tid; i < 48 * 64; i += 256) {
        int o = i & 63, ck = i >> 6;
        int oo = o0 + o;
        if (oo < Cout) Wt[(size_t)(c0 * 3 + ck) * Cout + oo] = ts[ck][o];
    }
}

// ---------------------------------------------------------------------------
// wsplit: enc_w2 [o][c][k] fp32 -> fragment-packed Wf.
// Block (k*16+cg)*32+og holds the MFMA A-fragment for (k, c-group cg,
// o-group og): 1024 ushorts = [hi 512 | lo 512], element (l,e) =
// w[og*16 + (l&15)][cg*32 + (l>>4)*8 + e]. One wave A-load = 1KB seq.
// ---------------------------------------------------------------------------
__global__ __launch_bounds__(256)
void wsplit(const float* __restrict__ W, unsigned short* __restrict__ Wf) {
    int o = blockIdx.x, k = blockIdx.y;
    int og = o >> 4;
    #pragma unroll
    for (int it = 0; it < 2; ++it) {
        int c = threadIdx.x + it * 256;
        float v = W[((size_t)o * Hc + c) * 3 + k];
        unsigned short h = f2bf(v);
        int cg = c >> 5;
        int l = (o & 15) | (((c >> 3) & 3) << 4);
        int e = c & 7;
        size_t base = ((size_t)((k * 16 + cg) * 32 + og) << 10) + l * 8 + e;
        Wf[base] = h;
        Wf[base + 512] = f2bf(v - bf2f(h));
    }
}

// ---------------------------------------------------------------------------
// wsplit80: dec_w2 [o][c][k] fp32 -> Wh2 [k][o][c] bf16 (hi only).
// ---------------------------------------------------------------------------
__global__ __launch_bounds__(256)
void wsplit80(const float* __restrict__ W, unsigned short* __restrict__ Wh) {
    int o = blockIdx.x, k = blockIdx.y;
    #pragma unroll
    for (int it = 0; it < 2; ++it) {
        int c = threadIdx.x + it * 256;
        Wh[((size_t)k * INC + o) * Hc + c] = f2bf(W[((size_t)o * Hc + c) * 3 + k]);
    }
}

// ---------------------------------------------------------------------------
// cbsplit: codebook [j][d] fp32 -> fragment-packed CBf.
// Block dg*64+jg: element (l,e) = cb[jg*16 + (l&15)][dg*32 + (l>>4)*8 + e].
// ---------------------------------------------------------------------------
__global__ __launch_bounds__(256)
void cbsplit(const float* __restrict__ CB, unsigned short* __restrict__ CBf) {
    int j = blockIdx.x;
    int jg = j >> 4;
    #pragma unroll
    for (int it = 0; it < 2; ++it) {
        int d = threadIdx.x + it * 256;
        float v = CB[(size_t)j * Dc + d];
        unsigned short h = f2bf(v);
        int dg = d >> 5;
        int l = (j & 15) | (((d >> 3) & 3) << 4);
        int e = d & 7;
        size_t base = ((size_t)(dg * 64 + jg) << 10) + l * 8 + e;
        CBf[base] = h;
        CBf[base + 512] = f2bf(v - bf2f(h));
    }
}

// ---------------------------------------------------------------------------
// conv_enc1: melsT [B,80,T] -> y1hl interleaved bf16 hi/lo, K=3, ReLU.
// Guard-row zeroing folded in (blocks at t-extremes zero their o-slice).
// ---------------------------------------------------------------------------
__global__ __launch_bounds__(256)
void conv_enc1(const float* __restrict__ X, const float* __restrict__ Wt,
               const float* __restrict__ bias, unsigned short* __restrict__ Yhl) {
    const int t0 = blockIdx.x * 64;
    const int o0 = blockIdx.y * 128;
    const int b  = blockIdx.z;
    union SharedU {
        struct { float Xs[16][72]; float Ws[48][132]; } a;
        float Ys[128][69];
    };
    __shared__ __align__(16) SharedU su;
    float (&Xs)[16][72]  = su.a.Xs;
    float (&Ws)[48][132] = su.a.Ws;
    const int tid = threadIdx.x;
    const int tx = tid & 15, ty = tid >> 4;
    float acc[8][4] = {};
    const float* Xb = X + (size_t)b * INC * Tn;

    // guard rows (t=-1 and t=Tn): zero this block's 4 o-groups (256 ushorts)
    if (blockIdx.x == 0 && tid < 64) {
        u16x4 z4 = {0, 0, 0, 0};
        *(u16x4*)(Yhl + ((size_t)(b * (Tn + 2)) * 16 + (o0 >> 5)) * 64 + tid * 4) = z4;
    }
    if (blockIdx.x == Tn / 64 - 1 && tid < 64) {
        u16x4 z4 = {0, 0, 0, 0};
        *(u16x4*)(Yhl + ((size_t)(b * (Tn + 2) + Tn + 1) * 16 + (o0 >> 5)) * 64
                  + tid * 4) = z4;
    }

    for (int c0 = 0; c0 < INC; c0 += 16) {
        for (int i = tid; i < 16 * 66; i += 256) {
            int cc = i / 66, tt = i % 66;
            int t = t0 + tt - 1;
            float v = 0.f;
            if (t >= 0 && t < Tn) v = Xb[(size_t)(c0 + cc) * Tn + t];
            Xs[cc][tt] = v;
        }
        for (int i = tid; i < 48 * 128; i += 256) {
            int o = i & 127, ck = i >> 7;
            Ws[ck][o] = Wt[(size_t)(c0 * 3 + ck) * Hc + o0 + o];
        }
        __syncthreads();
        #pragma unroll
        for (int cc = 0; cc < 16; ++cc) {
            float4 xa = *(const float4*)&Xs[cc][tx * 4];
            float2 xb2 = *(const float2*)&Xs[cc][tx * 4 + 4];
            float xv[6] = {xa.x, xa.y, xa.z, xa.w, xb2.x, xb2.y};
            #pragma unroll
            for (int k = 0; k < 3; ++k) {
                float4 wa = *(const float4*)&Ws[cc * 3 + k][ty * 4];
                float4 wb = *(const float4*)&Ws[cc * 3 + k][64 + ty * 4];
                float wv[8] = {wa.x, wa.y, wa.z, wa.w, wb.x, wb.y, wb.z, wb.w};
                #pragma unroll
                for (int i8 = 0; i8 < 8; ++i8)
                    #pragma unroll
                    for (int j = 0; j < 4; ++j)
                        acc[i8][j] = fmaf(wv[i8], xv[k + j], acc[i8][j]);
            }
        }
        __syncthreads();
    }
    #pragma unroll
    for (int og = 0; og < 2; ++og)
        #pragma unroll
        for (int oi = 0; oi < 4; ++oi) {
            int ol = og * 64 + ty * 4 + oi;
            float bv = bias[o0 + ol];
            const int i8 = og * 4 + oi;
            #pragma unroll
            for (int j = 0; j < 4; ++j)
                su.Ys[ol][tx * 4 + j] = fmaxf(acc[i8][j] + bv, 0.f);
        }
    __syncthreads();
    #pragma unroll
    for (int it = 0; it < 8; ++it) {
        int i = tid + it * 256;            // 2048 = 32 o-quads x 64 t
        int oq = i & 31, t = i >> 5;
        int o4 = o0 + oq * 4;
        u16x4 h, l;
        #pragma unroll
        for (int r = 0; r < 4; ++r) {
            float v = su.Ys[oq * 4 + r][t];
            unsigned short hh = f2bf(v);
            h[r] = hh;
            l[r] = f2bf(v - bf2f(hh));
        }
        size_t base = ((size_t)(b * (Tn + 2) + 1 + t0 + t) * 16 + (o4 >> 5)) * 64
                      + (o4 & 31);
        *(u16x4*)(Yhl + base) = h;
        *(u16x4*)(Yhl + base + 32) = l;
    }
}

// ---------------------------------------------------------------------------
// conv_mid_mfma: implicit GEMM, wave-autonomous staging (per-wave window +
// vmcnt(0), no K-loop barriers) + fragment-packed weights (1KB sequential
// A-loads) + explicit 3-phase A-prefetch pipeline (each A batch issued one
// full MFMA phase before use). Triple-split LDS-staged coalesced epilogue.
// Output bytes bit-identical to round 8. grid (Tn/128, Hc/128, B), block 256.
// ---------------------------------------------------------------------------
__global__ __launch_bounds__(256)
void conv_mid_mfma(const unsigned short* __restrict__ Xhl,
                   const unsigned short* __restrict__ Wf,
                   const float* __restrict__ bias,
                   unsigned short* __restrict__ Zt,
                   unsigned short* __restrict__ Lo2) {
    // XCD swizzle: lin%8 = XCD. XCD x -> b in {2x, 2x+1}; within: t-major, o inner.
    const int lin  = blockIdx.x + (blockIdx.y << 4) + (blockIdx.z << 6);
    const int slot = lin >> 3;                   // 0..127
    const int b  = ((lin & 7) << 1) | (slot >> 6);
    const int t0 = ((slot & 63) >> 2) << 7;      // t-block 0..15
    const int o0 = (slot & 3) << 7;              // o-block 0..3
    // 4 waves x 2 bufs x 72 rows x 64 ushorts = 73728 B
    __shared__ __align__(16) unsigned short pool[4 * 2 * 72 * 64];
    const int tid  = threadIdx.x;
    const int lane = tid & 63;
    const int wave = tid >> 6;
    const int wm = wave >> 1, wn = wave & 1;
    const int m16 = lane & 15;
    const int q = lane >> 4;
    const int lrow = lane >> 3;
    const int lchk = (lane & 7) ^ lrow;
    const int ogb = (o0 >> 4) + wm * 4;          // this wave's o-group base
    unsigned short* XW = pool + wave * (2 * 72 * 64);
    const unsigned short* XbW = Xhl + ((size_t)b * (Tn + 2) + t0 + wn * 64) * 1024
                                + (size_t)lrow * 1024 + lchk * 8;

    f32x4 acc[4][4];
    #pragma unroll
    for (int mt = 0; mt < 4; ++mt)
        #pragma unroll
        for (int nt = 0; nt < 4; ++nt)
            acc[mt][nt] = (f32x4){0.f, 0.f, 0.f, 0.f};

    // prologue: stage c-group 0 into buf 0; preload A(k=0, cg=0)
    #pragma unroll
    for (int i = 0; i < 9; ++i)
        async16(XbW + (size_t)i * 8192, XW + i * 512);
    AFrag A0, A1, A2;
    load_afrag(Wf, (0 * 16 + 0) * 32 + ogb, lane, A0);

#define COMPUTE_K(KK, AF)                                                   \
    {                                                                       \
        _Pragma("unroll")                                                   \
        for (int nt = 0; nt < 4; ++nt) {                                    \
            int row = nt * 16 + m16 + (KK);                                 \
            const unsigned short* rp = XW + buf * 4608 + row * 64;          \
            int ph = (q ^ (row & 7)) * 8;                                   \
            union { bf16x8 v; uint4 u; } bh, bl;                            \
            bh.u = *(const uint4*)(rp + ph);                                \
            bl.u = *(const uint4*)(rp + (ph ^ 32));                         \
            _Pragma("unroll")                                               \
            for (int mt = 0; mt < 4; ++mt)                                  \
                acc[mt][nt] = __builtin_amdgcn_mfma_f32_16x16x32_bf16(      \
                    (AF).h[mt], bh.v, acc[mt][nt], 0, 0, 0);                \
            _Pragma("unroll")                                               \
            for (int mt = 0; mt < 4; ++mt)                                  \
                acc[mt][nt] = __builtin_amdgcn_mfma_f32_16x16x32_bf16(      \
                    (AF).l[mt], bh.v, acc[mt][nt], 0, 0, 0);                \
            _Pragma("unroll")                                               \
            for (int mt = 0; mt < 4; ++mt)                                  \
                acc[mt][nt] = __builtin_amdgcn_mfma_f32_16x16x32_bf16(      \
                    (AF).h[mt], bl.v, acc[mt][nt], 0, 0, 0);                \
        }                                                                   \
    }

    for (int c0 = 0; c0 < Hc; c0 += 32) {
        const int cg = c0 >> 5;
        const int buf = cg & 1;
        wave_vm_drain();                  // staging + A0 ready for this wave
        if (c0 + 32 < Hc) {
            const unsigned short* src = XbW + (size_t)(cg + 1) * 64;
            #pragma unroll
            for (int i = 0; i < 9; ++i)
                async16(src + (size_t)i * 8192, XW + (buf ^ 1) * 4608 + i * 512);
        }
        load_afrag(Wf, (1 * 16 + cg) * 32 + ogb, lane, A1);   // cover: k0 phase
        COMPUTE_K(0, A0);
        load_afrag(Wf, (2 * 16 + cg) * 32 + ogb, lane, A2);   // cover: k1 phase
        COMPUTE_K(1, A1);
        // next c-group's k=0 (cg=16 reads in-bounds garbage, never used)
        load_afrag(Wf, (0 * 16 + cg + 1) * 32 + ogb, lane, A0);
        COMPUTE_K(2, A2);
    }
#undef COMPUTE_K

    // epilogue: stage through LDS (reuse pool), coalesced 512B/256B rows.
    __syncthreads();                     // all waves done with pool
    unsigned short* SZ = pool;           // [32][264]
    unsigned short* SL = pool + 32 * 264;// [32][136]
    unsigned short* Lb = Lo2 + (size_t)b * Tn * 512;
    const int g0 = o0 >> 5;
    #pragma unroll
    for (int p = 0; p < 4; ++p) {
        if (p) __syncthreads();          // staging buffer free
        if (wn == (p >> 1)) {
            #pragma unroll
            for (int nt2 = 0; nt2 < 2; ++nt2) {
                int nt = (p & 1) * 2 + nt2;
                int srow = nt2 * 16 + m16;   // 0..31
                #pragma unroll
                for (int mt = 0; mt < 4; ++mt) {
                    int lo = wm * 64 + mt * 16 + q * 4;   // local o 0..127
                    int ob = o0 + lo;
                    float4 bq = *(const float4*)&bias[ob];
                    float bqa[4] = {bq.x, bq.y, bq.z, bq.w};
                    u16x4 h, l, l2;
                    #pragma unroll
                    for (int r = 0; r < 4; ++r) {
                        float v = acc[mt][nt][r] + bqa[r];
                        unsigned short hh = f2bf(v);
                        float r1 = v - bf2f(hh);
                        unsigned short ll = f2bf(r1);
                        h[r] = hh;
                        l[r] = ll;
                        l2[r] = f2bf(r1 - bf2f(ll));
                    }
                    int gb = (lo >> 5) * 64 + (lo & 31);
                    *(u16x4*)&SZ[srow * 264 + gb] = h;
                    *(u16x4*)&SZ[srow * 264 + gb + 32] = l;
                    *(u16x4*)&SL[srow * 136 + lo] = l2;
                }
            }
        }
        __syncthreads();                 // staging data ready
        // Zt: 32 rows x 512B contiguous (64 lanes x 8B per row)
        #pragma unroll
        for (int it = 0; it < 8; ++it) {
            int i = tid + it * 256;
            int row = i >> 6, c = i & 63;
            *(u16x4*)(Zt + ((size_t)(b * Tn + t0 + p * 32 + row) * 16 + g0) * 64
                      + c * 4) = *(u16x4*)&SZ[row * 264 + c * 4];
        }
        // lo2: 32 rows x 256B contiguous (32 lanes x 8B per row)
        #pragma unroll
        for (int it = 0; it < 4; ++it) {
            int i = tid + it * 256;
            int row = i >> 5, c = i & 31;
            *(u16x4*)(Lb + (size_t)(t0 + p * 32 + row) * 512 + o0 + c * 4)
                = *(u16x4*)&SL[row * 136 + c * 4];
        }
    }
}

// ---------------------------------------------------------------------------
// dec2_mfma: recon = conv(y3t bf16, dec_w2) + b. async16 + XOR-swizzle,
// 64-c groups (single bf16), double-buffered. grid (Tn/128, 1, B), block 256.
// ---------------------------------------------------------------------------
__global__ __launch_bounds__(256)
void dec2_mfma(const unsigned short* __restrict__ Xt,
               const unsigned short* __restrict__ Wh2,
               const float* __restrict__ bias, float* __restrict__ OUT) {
    const int t0 = blockIdx.x * 128;
    const int b  = blockIdx.z;
    __shared__ __align__(16) unsigned short XL[2][136 * 64];  // 2 x 17408 B
    const int tid = threadIdx.x;
    const int lane = tid & 63;
    const int wave = tid >> 6;
    const int wn = wave;               // wave = t-quadrant (32 t each)
    const int m16 = lane & 15;
    const int q = lane >> 4;
    const int lrow = lane >> 3;
    const int lchk = (lane & 7) ^ lrow;
    const unsigned short* Xb = Xt + ((size_t)b * (Tn + 2) + t0) * 512
                               + (size_t)lrow * 512 + lchk * 8;

    f32x4 acc[5][2];
    #pragma unroll
    for (int mt = 0; mt < 5; ++mt)
        #pragma unroll
        for (int nt = 0; nt < 2; ++nt)
            acc[mt][nt] = (f32x4){0.f, 0.f, 0.f, 0.f};

    #pragma unroll
    for (int i = 0; i < 5; ++i) {
        int ii = wave + i * 4;
        if (ii < 17)
            async16(Xb + (size_t)ii * 4096, &XL[0][ii * 512]);
    }

    for (int c0 = 0; c0 < Hc; c0 += 64) {
        const int buf = (c0 >> 6) & 1;
        __syncthreads();
        if (c0 + 64 < Hc) {
            const unsigned short* src = Xb + (size_t)((c0 >> 6) + 1) * 64;
            #pragma unroll
            for (int i = 0; i < 5; ++i) {
                int ii = wave + i * 4;
                if (ii < 17)
                    async16(src + (size_t)ii * 4096, &XL[buf ^ 1][ii * 512]);
            }
        }
        #pragma unroll
        for (int k = 0; k < 3; ++k) {
            #pragma unroll
            for (int sub = 0; sub < 2; ++sub) {
                int c = c0 + sub * 32;
                bf16x8 Ah[5];
                #pragma unroll
                for (int mt = 0; mt < 5; ++mt) {
                    int o = mt * 16 + m16;
                    Ah[mt] = *(const bf16x8*)(Wh2 + ((size_t)(k * INC + o)) * Hc
                                              + c + q * 8);
                }
                #pragma unroll
                for (int nt = 0; nt < 2; ++nt) {
                    int row = wn * 32 + nt * 16 + m16 + k;   // 0..129
                    const unsigned short* rp = &XL[buf][row * 64];
                    int p = sub * 4 + q;
                    int ph = (p ^ (row & 7)) * 8;
                    union { bf16x8 v; uint4 u; } bh;
                    bh.u = *(const uint4*)(rp + ph);
                    #pragma unroll
                    for (int mt = 0; mt < 5; ++mt)
                        acc[mt][nt] = __builtin_amdgcn_mfma_f32_16x16x32_bf16(
                            Ah[mt], bh.v, acc[mt][nt], 0, 0, 0);
                }
            }
        }
    }
    #pragma unroll
    for (int mt = 0; mt < 5; ++mt) {
        float4 bq = *(const float4*)&bias[mt * 16 + q * 4];
        #pragma unroll
        for (int nt = 0; nt < 2; ++nt) {
            int t = t0 + wn * 32 + nt * 16 + m16;
            float4 r;
            r.x = acc[mt][nt][0] + bq.x;
            r.y = acc[mt][nt][1] + bq.y;
            r.z = acc[mt][nt][2] + bq.z;
            r.w = acc[mt][nt][3] + bq.w;
            *(float4*)(OUT + ((size_t)b * Tn + t) * INC + mt * 16 + q * 4) = r;
        }
    }
}

// ---------------------------------------------------------------------------
// vq_mfma: approx distances via 3xbf16 MFMA GEMM reading Zt.
// Wave-autonomous staging + fragment-packed codebook + one-iteration
// register prefetch of CB fragments (unroll-by-2, parity register sets).
// grid (BT/128, NCODE/128) = 2048 blocks, block 256.
// ---------------------------------------------------------------------------
__global__ __launch_bounds__(256)
void vq_mfma(const unsigned short* __restrict__ Zt,
             const unsigned short* __restrict__ CBf,
             const float* __restrict__ CN,
             float* __restrict__ candv, int* __restrict__ candi,
             float* __restrict__ cand2v) {
    // XCD swizzle: lin%8 = XCD; XCD x -> nb in [32x, 32x+32) (2 batches), all jb.
    const int lin  = blockIdx.x + (blockIdx.y << 8);
    const int slotB = lin >> 3;                  // 0..255
    const int nb = ((lin & 7) << 5) | (slotB & 31);
    const int jb = slotB >> 5;                   // 0..7
    const int b  = nb >> 4;
    const int t0 = (nb & 15) * 128;
    const int jbase = jb * 128;
    // 4 waves x 2 bufs x 64 rows x 64 ushorts = 65536 B; reduction aliased.
    __shared__ __align__(16) unsigned short vpool[4 * 2 * 64 * 64];
    float* RV = (float*)vpool;
    int*   RI = (int*)((char*)vpool + 4096);
    float* R2 = (float*)((char*)vpool + 8192);

    const int tid = threadIdx.x;
    const int lane = tid & 63;
    const int wave = tid >> 6;
    const int wm = wave >> 1, wn = wave & 1;
    const int m16 = lane & 15;
    const int q = lane >> 4;
    const int lrow = lane >> 3;
    const int lchk = (lane & 7) ^ lrow;
    const int jgb = jb * 8 + wm * 4;             // this wave's j-group base
    unsigned short* XW = vpool + wave * (2 * 64 * 64);
    const unsigned short* ZbW = Zt + (size_t)(b * Tn + t0 + wn * 64) * 1024
                                + (size_t)lrow * 1024 + lchk * 8;

    f32x4 acc[4][4];
    #pragma unroll
    for (int mt = 0; mt < 4; ++mt)
        #pragma unroll
        for (int nt = 0; nt < 4; ++nt)
            acc[mt][nt] = (f32x4){0.f, 0.f, 0.f, 0.f};

    // prologue: stage d-group 0 into buf 0; preload CB fragments for dg 0
    #pragma unroll
    for (int i = 0; i < 8; ++i)
        async16(ZbW + (size_t)i * 8192, XW + i * 512);
    AFrag Aa, Ab;
    load_afrag(CBf, 0 * 64 + jgb, lane, Aa);

#define VQ_COMPUTE(AF, BUF)                                                 \
    {                                                                       \
        _Pragma("unroll")                                                   \
        for (int nt = 0; nt < 4; ++nt) {                                    \
            int row = nt * 16 + m16;                                        \
            const unsigned short* rp = XW + (BUF) * 4096 + row * 64;        \
            int ph = (q ^ (row & 7)) * 8;                                   \
            union { bf16x8 v; uint4 u; } bh, bl;                            \
            bh.u = *(const uint4*)(rp + ph);                                \
            bl.u = *(const uint4*)(rp + (ph ^ 32));                         \
            _Pragma("unroll")                                               \
            for (int mt = 0; mt < 4; ++mt)                                  \
                acc[mt][nt] = __builtin_amdgcn_mfma_f32_16x16x32_bf16(      \
                    (AF).h[mt], bh.v, acc[mt][nt], 0, 0, 0);                \
            _Pragma("unroll")                                               \
            for (int mt = 0; mt < 4; ++mt)                                  \
                acc[mt][nt] = __builtin_amdgcn_mfma_f32_16x16x32_bf16(      \
                    (AF).l[mt], bh.v, acc[mt][nt], 0, 0, 0);                \
            _Pragma("unroll")                                               \
            for (int mt = 0; mt < 4; ++mt)                                  \
                acc[mt][nt] = __builtin_amdgcn_mfma_f32_16x16x32_bf16(      \
                    (AF).h[mt], bl.v, acc[mt][nt], 0, 0, 0);                \
        }                                                                   \
    }

    for (int it = 0; it < 16; it += 2) {
        // even sub-iteration: buf 0, compute Aa, prefetch dg it+1 -> Ab
        wave_vm_drain();
        {
            const unsigned short* src = ZbW + (size_t)(it + 1) * 64;
            #pragma unroll
            for (int i = 0; i < 8; ++i)
                async16(src + (size_t)i * 8192, XW + 4096 + i * 512);
        }
        load_afrag(CBf, (it + 1) * 64 + jgb, lane, Ab);
        VQ_COMPUTE(Aa, 0);
        // odd sub-iteration: buf 1, compute Ab, prefetch dg it+2 -> Aa
        wave_vm_drain();
        if (it + 2 < 16) {
            const unsigned short* src = ZbW + (size_t)(it + 2) * 64;
            #pragma unroll
            for (int i = 0; i < 8; ++i)
                async16(src + (size_t)i * 8192, XW + i * 512);
            load_afrag(CBf, (it + 2) * 64 + jgb, lane, Aa);
        }
        VQ_COMPUTE(Ab, 1);
    }
#undef VQ_COMPUTE
    __syncthreads();                      // pool reuse for reduction

    float cn4[4][4];
    #pragma unroll
    for (int mt = 0; mt < 4; ++mt) {
        float4 c = *(const float4*)&CN[jbase + wm * 64 + mt * 16 + q * 4];
        cn4[mt][0] = c.x; cn4[mt][1] = c.y; cn4[mt][2] = c.z; cn4[mt][3] = c.w;
    }
    #pragma unroll
    for (int nt = 0; nt < 4; ++nt) {
        int t = wn * 64 + nt * 16 + m16;
        float v1 = 1e30f, v2 = 1e30f;
        int i1 = 0;
        #pragma unroll
        for (int mt = 0; mt < 4; ++mt)
            #pragma unroll
            for (int r = 0; r < 4; ++r) {
                float d = fmaf(-2.f, acc[mt][nt][r], cn4[mt][r]);
                int j = jbase + wm * 64 + mt * 16 + q * 4 + r;
                if (d < v1 || (d == v1 && j < i1)) { v2 = v1; v1 = d; i1 = j; }
                else if (d < v2) v2 = d;
            }
        int slotw = wm * 4 + q;
        RV[t * 8 + slotw] = v1;
        RI[t * 8 + slotw] = i1;
        R2[t * 8 + slotw] = v2;
    }
    __syncthreads();
    if (tid < 128) {
        int t = tid;
        float v1 = RV[t * 8], v2 = R2[t * 8];
        int i1 = RI[t * 8];
        #pragma unroll
        for (int s = 1; s < 8; ++s) {
            float a1 = RV[t * 8 + s], a2 = R2[t * 8 + s];
            int ai = RI[t * 8 + s];
            if (a1 < v1 || (a1 == v1 && ai < i1)) {
                v2 = fminf(v1, a2); v1 = a1; i1 = ai;
            } else {
                v2 = fminf(v2, a1);
            }
        }
        int n = b * Tn + t0 + t;
        candv[(size_t)jb * BT + n] = v1;
        candi[(size_t)jb * BT + n] = i1;
        cand2v[(size_t)jb * BT + n] = v2;
    }
}

// ---------------------------------------------------------------------------
// vq_reduce2: merge 8 j-block candidates; flag near-ties for exact rescore.
// ---------------------------------------------------------------------------
__global__ __launch_bounds__(256)
void vq_reduce2(const float* __restrict__ candv, const int* __restrict__ candi,
                const float* __restrict__ cand2v, int* __restrict__ idxI,
                float* __restrict__ idxf, int* __restrict__ flagn,
                int* __restrict__ flaglist) {
    int n = blockIdx.x * 256 + threadIdx.x;
    float v1 = candv[n], v2 = cand2v[n];
    int i1 = candi[n];
    #pragma unroll
    for (int jq = 1; jq < 8; ++jq) {
        float a1 = candv[(size_t)jq * BT + n];
        float a2 = cand2v[(size_t)jq * BT + n];
        int ai = candi[(size_t)jq * BT + n];
        if (a1 < v1 || (a1 == v1 && ai < i1)) {
            v2 = fminf(v1, a2); v1 = a1; i1 = ai;
        } else {
            v2 = fminf(v2, a1);
        }
    }
    idxI[n] = i1;
    idxf[n] = (float)i1;
    if (v2 - v1 < MARGIN) {
        int s = atomicAdd(flagn, 1);
        flaglist[s] = n;
    }
}

// ---------------------------------------------------------------------------
// vq_rescue: near-exact re-score of flagged positions over all 1024 codes.
// z reconstructed as hi+lo+lo2 (error <= 2^-27 |z|).
// ---------------------------------------------------------------------------
__global__ __launch_bounds__(256)
void vq_rescue(const int* __restrict__ flagn, const int* __restrict__ flaglist,
               const unsigned short* __restrict__ Zt,
               const unsigned short* __restrict__ Lo2,
               const float* __restrict__ CB,
               const float* __restrict__ CN, int* __restrict__ idxI,
               float* __restrict__ idxf) {
    __shared__ float zs[512];
    __shared__ float rvv[256];
    __shared__ int   rii[256];
    const int nf = *flagn;
    for (int f = blockIdx.x; f < nf; f += gridDim.x) {
        int n = flaglist[f];
        __syncthreads();
        #pragma unroll
        for (int it = 0; it < 2; ++it) {
            int d = threadIdx.x + it * 256;
            const unsigned short* zr = Zt + ((size_t)n * 16 + (d >> 5)) * 64
                                       + (d & 31);
            zs[d] = bf2f(zr[0]) + bf2f(zr[32]) + bf2f(Lo2[(size_t)n * 512 + d]);
        }
        __syncthreads();
        float bv = 1e30f;
        int bi = 0;
        #pragma unroll
        for (int jj = 0; jj < 4; ++jj) {
            int j = threadIdx.x * 4 + jj;
            const float* cr = CB + (size_t)j * Dc;
            float dot = 0.f;
            for (int d = 0; d < Dc; ++d) dot = fmaf(zs[d], cr[d], dot);
            float dist = fmaf(-2.f, dot, CN[j]);
            if (dist < bv || (dist == bv && j < bi)) { bv = dist; bi = j; }
        }
        rvv[threadIdx.x] = bv;
        rii[threadIdx.x] = bi;
        __syncthreads();
        for (int off = 128; off > 0; off >>= 1) {
            if (threadIdx.x < off) {
                float ov = rvv[threadIdx.x + off];
                int oi = rii[threadIdx.x + off];
                if (ov < rvv[threadIdx.x] ||
                    (ov == rvv[threadIdx.x] && oi < rii[threadIdx.x])) {
                    rvv[threadIdx.x] = ov; rii[threadIdx.x] = oi;
                }
            }
            __syncthreads();
        }
        if (threadIdx.x == 0) {
            idxI[n] = rii[0];
            idxf[n] = (float)rii[0];
        }
    }
}

// ---------------------------------------------------------------------------
// gemm_g: G[j][kk*512+o] = sum_c CB[j][c] * dec_w1[o][c][kk].
// ---------------------------------------------------------------------------
__global__ __launch_bounds__(256)
void gemm_g(const float* __restrict__ CBt, const float* __restrict__ Wt,
            float* __restrict__ G) {
    const int j0 = blockIdx.x * 64;
    const int kk = blockIdx.y >> 2;
    const int o0 = (blockIdx.y & 3) * 128;
    __shared__ __align__(16) float As[16][68];
    __shared__ __align__(16) float Bs[16][132];
    const int tid = threadIdx.x;
    const int tx = tid & 15, ty = tid >> 4;
    float acc[4][8] = {};

    for (int c0 = 0; c0 < Dc; c0 += 16) {
        {
            int cc = tid >> 4, j4 = tid & 15;
            *(float4*)&As[cc][j4 * 4] =
                *(const float4*)&CBt[(size_t)(c0 + cc) * NCODE + j0 + j4 * 4];
        }
        #pragma unroll
        for (int it = 0; it < 2; ++it) {
            int i = tid + it * 256;
            int cc = i >> 5, o4 = i & 31;
            *(float4*)&Bs[cc][o4 * 4] =
                *(const float4*)&Wt[(size_t)((c0 + cc) * 3 + kk) * Hc + o0 + o4 * 4];
        }
        __syncthreads();
        #pragma unroll
        for (int cc = 0; cc < 16; ++cc) {
            float4 a = *(const float4*)&As[cc][tx * 4];
            float av[4] = {a.x, a.y, a.z, a.w};
            float4 b0 = *(const float4*)&Bs[cc][ty * 4];
            float4 b1 = *(const float4*)&Bs[cc][64 + ty * 4];
            float bv[8] = {b0.x, b0.y, b0.z, b0.w, b1.x, b1.y, b1.z, b1.w};
            #pragma unroll
            for (int jj = 0; jj < 4; ++jj)
                #pragma unroll
                for (int oo = 0; oo < 8; ++oo)
                    acc[jj][oo] = fmaf(av[jj], bv[oo], acc[jj][oo]);
        }
        __syncthreads();
    }
    #pragma unroll
    for (int jj = 0; jj < 4; ++jj) {
        int j = j0 + tx * 4 + jj;
        float* gp = G + (size_t)j * 1536 + kk * 512 + o0;
        *(float4*)(gp + ty * 4) = *(float4*)&acc[jj][0];
        *(float4*)(gp + 64 + ty * 4) = *(float4*)&acc[jj][4];
    }
}

// ---------------------------------------------------------------------------
// dec_y3: y3t[b][t][o] (bf16, rows of 512, guards folded in) =
//   f2bf(relu(b1[o] + sum_kk G[idx[b][t+kk-1]][kk*512+o])).
// ---------------------------------------------------------------------------
__global__ __launch_bounds__(256)
void dec_y3(const int* __restrict__ idx, const float* __restrict__ G,
            const float* __restrict__ bias, unsigned short* __restrict__ Yt) {
    const int t0 = blockIdx.x * 64;
    const int o0 = blockIdx.y * 128;
    const int b  = blockIdx.z;
    const int tid = threadIdx.x;
    __shared__ int sidx[66];
    __shared__ __align__(16) float Ys[128][68];

    // guard rows (t=-1 and t=Tn): zero this block's o-slice (128 ushorts)
    if (blockIdx.x == 0 && tid < 32) {
        u16x4 z4 = {0, 0, 0, 0};
        *(u16x4*)(Yt + (size_t)(b * (Tn + 2)) * 512 + o0 + tid * 4) = z4;
    }
    if (blockIdx.x == Tn / 64 - 1 && tid < 32) {
        u16x4 z4 = {0, 0, 0, 0};
        *(u16x4*)(Yt + (size_t)(b * (Tn + 2) + Tn + 1) * 512 + o0 + tid * 4) = z4;
    }

    if (tid < 66) {
        int t = t0 + tid - 1;
        sidx[tid] = (t >= 0 && t < Tn) ? idx[b * Tn + t] : -1;
    }
    __syncthreads();

    const int o = tid & 127;
    const int half = tid >> 7;
    float acc[32] = {};
    #pragma unroll
    for (int kk = 0; kk < 3; ++kk) {
        const float* Gk = G + (size_t)kk * 512 + o0 + o;
        #pragma unroll
        for (int k = 0; k < 32; ++k) {
            int j = sidx[half + 2 * k + kk];
            if (j >= 0) acc[k] += Gk[(size_t)j * 1536];
        }
    }
    float bv = bias[o0 + o];
    #pragma unroll
    for (int k = 0; k < 32; ++k)
        Ys[o][half + 2 * k] = fmaxf(acc[k] + bv, 0.f);
    __syncthreads();

    unsigned short* Yb = Yt + ((size_t)(b * (Tn + 2) + 1 + t0)) * 512 + o0;
    #pragma unroll
    for (int it = 0; it < 8; ++it) {
        int i = tid + it * 256;            // 2048 = 32 o-quads x 64 t
        int t = i >> 5, oq = i & 31;
        u16x4 h;
        #pragma unroll
        for (int r = 0; r < 4; ++r)
            h[r] = f2bf(Ys[oq * 4 + r][t]);
        *(u16x4*)(Yb + (size_t)t * 512 + oq * 4) = h;
    }
}

// ---------------------------------------------------------------------------
extern "C" void kernel_launch(void* const* d_in, const int* in_sizes, int n_in,
                              void* d_out, int out_size, void* d_ws, size_t ws_size,
                              hipStream_t stream) {
    const float* mels    = (const float*)d_in[0];
    const float* enc_w1  = (const float*)d_in[1];
    const float* enc_b1  = (const float*)d_in[2];
    const float* enc_w2  = (const float*)d_in[3];
    const float* enc_b2  = (const float*)d_in[4];
    const float* codebook= (const float*)d_in[5];
    const float* dec_w1  = (const float*)d_in[6];
    const float* dec_b1  = (const float*)d_in[7];
    const float* dec_w2  = (const float*)d_in[8];
    const float* dec_b2  = (const float*)d_in[9];

    float* out = (float*)d_out;
    float* recon = out;                 // [B,T,80]
    float* idxf  = out + RECON_N;       // [B,T] as float

    const size_t ACT = (size_t)Bsz * Hc * Tn;          // 16,777,216 floats
    const size_t Y1HL_U = (size_t)Bsz * (Tn + 2) * 1024 + 16384; // ushorts+slack
    const size_t R2F = Y1HL_U / 2;                      // floats

    // Region R1 (67 MB): Zt interleaved hi/lo (conv_mid out, vq+rescue read)
    //                    -> later y3t bf16 (dec path, after rescue)
    unsigned short* Zt  = (unsigned short*)d_ws;        // [BT*1024] ushorts
    unsigned short* y3t = (unsigned short*)d_ws;        // aliases Zt post-rescue
    // Region R2 (67 MB): y1hl interleaved (enc1 out, conv_mid in)
    float* r2 = (float*)d_ws + ACT;
    unsigned short* y1hl = (unsigned short*)r2;
    // small region
    float* sm    = r2 + R2F;
    int*   idxI  = (int*)sm;                            // [BT]
    float* cn    = (float*)(idxI + BT);                 // [NCODE]
    float* cbt   = cn + NCODE;                          // [Dc*NCODE]
    float* wt1   = cbt + (size_t)Dc * NCODE;            // enc_w1t: 80*3*512
    float* wt3   = wt1 + (size_t)INC * 3 * Hc;          // dec_w1t: 512*3*512
    float* candv = wt3 + (size_t)Dc * 3 * Hc;           // [8*BT]
    float* cand2v= candv + (size_t)8 * BT;              // [8*BT]
    int*   candi = (int*)(cand2v + (size_t)8 * BT);     // [8*BT]
    int*   flagn = candi + (size_t)8 * BT;              // [4]
    int*   flaglist = flagn + 4;                        // [BT]
    float* G     = (float*)(flaglist + BT);             // [NCODE*1536]
    unsigned short* wf  = (unsigned short*)(G + (size_t)NCODE * 1536); // [3*Hc*1024]
    unsigned short* cbf = wf + (size_t)3 * Hc * 1024;                  // [NCODE*1024]
    unsigned short* wh2 = cbf + (size_t)NCODE * 1024;                  // [3*INC*Hc]
    float* melsT = (float*)(wh2 + (size_t)3 * INC * Hc);               // [B,80,T]
    // lo2 residual plane [BT*512] ushorts; aliases melsT (dead after enc1)
    unsigned short* lo2 = (unsigned short*)melsT;

    dim3 blk(256);
    hipMemsetAsync(flagn, 0, 16, stream);
    // prep: norms + transposes + bf16 splits (fragment-packed)
    code_norms<<<dim3(NCODE), dim3(64), 0, stream>>>(codebook, cn);
    cb_transpose<<<dim3(NCODE / 64, Dc / 64), blk, 0, stream>>>(codebook, cbt);
    mels_transpose<<<dim3(Tn / 64, Bsz), blk, 0, stream>>>(mels, melsT);
    wt_transpose<<<dim3(Hc / 64, INC / 16), blk, 0, stream>>>(enc_w1, wt1, INC, Hc);
    wsplit<<<dim3(Hc, 3), blk, 0, stream>>>(enc_w2, wf);
    cbsplit<<<dim3(NCODE), blk, 0, stream>>>(codebook, cbf);
    wt_transpose<<<dim3(Hc / 64, Dc / 16), blk, 0, stream>>>(dec_w1, wt3, Dc, Hc);
    wsplit80<<<dim3(INC, 3), blk, 0, stream>>>(dec_w2, wh2);
    // decoder conv1 folded matrix (independent of activations)
    gemm_g<<<dim3(NCODE / 64, 12), blk, 0, stream>>>(cbt, wt3, G);
    // encoder (enc1 writes interleaved y1hl + its guard rows)
    conv_enc1<<<dim3(Tn / 64, Hc / 128, Bsz), blk, 0, stream>>>(melsT, wt1, enc_b1,
                                                                y1hl);
    // conv_mid: wave-autonomous dbuf + A-prefetch; writes Zt + lo2
    conv_mid_mfma<<<dim3(Tn / 128, Hc / 128, Bsz), blk, 0, stream>>>(y1hl, wf,
                                                                     enc_b2,
                                                                     Zt, lo2);
    // vector quantization: MFMA approx + margin-guarded near-exact rescue
    vq_mfma<<<dim3(BT / 128, NCODE / 128), blk, 0, stream>>>(Zt, cbf, cn,
                                                             candv, candi, cand2v);
    vq_reduce2<<<dim3(BT / 256), blk, 0, stream>>>(candv, candi, cand2v, idxI,
                                                   idxf, flagn, flaglist);
    vq_rescue<<<dim3(128), blk, 0, stream>>>(flagn, flaglist, Zt, lo2, codebook,
                                             cn, idxI, idxf);
    // decoder: conv1 via gather of G rows (bf16 out + guards), conv2 via MFMA
    dec_y3<<<dim3(Tn / 64, 4, Bsz), blk, 0, stream>>>(idxI, G, dec_b1, y3t);
    dec2_mfma<<<dim3(Tn / 128, 1, Bsz), blk, 0, stream>>>(y3t, wh2, dec_b2, recon);
}